// Round 1
// baseline (147.173 us; speedup 1.0000x reference)
//
#include <hip/hip_runtime.h>
#include <hip/hip_bf16.h>
#include <stdint.h>

// BQuantConv1d: out = x @ W^T + bias, where W[f,n] = sum_k scale[k,f]*sign_k[f,n],
// sign from bit (7 - n%8) of binary[k, f, n/8].
// Strategy: decode W -> bf16 once (reused by all M-tiles), cast x -> bf16,
// then m97-structure 128x128 bf16 MFMA GEMM (BK=64, 4 waves, global_load_lds w=16).

#define BITS 8
#define NF   4096
#define NXX  1024
#define GRP  (NXX / 8)

#define BM 128
#define BN 128
#define BK 64

typedef __attribute__((ext_vector_type(4))) float f32x4;
typedef __attribute__((ext_vector_type(8))) short bf16x8;

// ---- kernel 1: cast x fp32 -> bf16, 8 elems/thread (32B read, 16B write) ----
__global__ __launch_bounds__(256) void k_cast_x(const float* __restrict__ x,
                                                __hip_bfloat16* __restrict__ xb) {
    int i = blockIdx.x * 256 + threadIdx.x;
    const float4* xp = (const float4*)x;
    float4 a = xp[2 * i], b = xp[2 * i + 1];
    union { __hip_bfloat16 h[8]; int4 v; } u;
    u.h[0] = __float2bfloat16(a.x);
    u.h[1] = __float2bfloat16(a.y);
    u.h[2] = __float2bfloat16(a.z);
    u.h[3] = __float2bfloat16(a.w);
    u.h[4] = __float2bfloat16(b.x);
    u.h[5] = __float2bfloat16(b.y);
    u.h[6] = __float2bfloat16(b.z);
    u.h[7] = __float2bfloat16(b.w);
    ((int4*)xb)[i] = u.v;
}

// ---- kernel 2: decode packed sign-planes -> effective weight W (NF x NX) bf16 ----
// one thread per (f, g): reads 8 packed bytes (one per bit-plane) + 8 scales,
// writes 8 bf16 weights (16B coalesced).
__global__ __launch_bounds__(256) void k_decode_w(const int* __restrict__ binary,
                                                  const float* __restrict__ scale,
                                                  __hip_bfloat16* __restrict__ Wb) {
    int idx = blockIdx.x * 256 + threadIdx.x;   // 0 .. NF*GRP-1
    int f = idx >> 7;                           // idx / GRP  (GRP=128)
    int g = idx & (GRP - 1);
    float sc[BITS];
    int   bv[BITS];
#pragma unroll
    for (int k = 0; k < BITS; ++k) {
        sc[k] = scale[k * NF + f];
        bv[k] = binary[(size_t)(k * NF + f) * GRP + g];
    }
    union { __hip_bfloat16 h[8]; int4 v; } u;
#pragma unroll
    for (int j = 0; j < 8; ++j) {               // element j uses bit (7-j)
        float s = 0.f;
#pragma unroll
        for (int k = 0; k < BITS; ++k)
            s += ((bv[k] >> (7 - j)) & 1) ? sc[k] : -sc[k];
        u.h[j] = __float2bfloat16(s);
    }
    ((int4*)Wb)[idx] = u.v;                     // W[f][g*8 .. g*8+7]
}

// ---- kernel 3: C[M,N] = A[M,K] * B[N,K]^T + bias, bf16 inputs, fp32 out ----
// m97 structure: 128x128 tile, BK=64, 256 threads = 2x2 waves of 64x64,
// global_load_lds dwordx4 staging, 2 barriers per K-step.
__global__ __launch_bounds__(256) void k_gemm_bt(const __hip_bfloat16* __restrict__ A,
                                                 const __hip_bfloat16* __restrict__ B,
                                                 const float* __restrict__ bias,
                                                 float* __restrict__ C,
                                                 int M, int N, int K) {
    __shared__ __hip_bfloat16 sA[BM * BK];   // 16 KB
    __shared__ __hip_bfloat16 sB[BN * BK];   // 16 KB
    const int tid  = threadIdx.x;
    const int lane = tid & 63;
    const int wave = tid >> 6;
    const int wm = wave >> 1, wn = wave & 1;     // 2x2 wave grid, 64x64 per wave
    const int m0 = blockIdx.y * BM;
    const int n0 = blockIdx.x * BN;
    const int lrow = lane & 15;                  // fragment row (A) / col (B)
    const int lkq  = lane >> 4;                  // K-octet index 0..3

    f32x4 acc[4][4] = {};

    for (int kt = 0; kt < K; kt += BK) {
        __syncthreads();   // previous tile's ds_reads done before overwrite
#pragma unroll
        for (int j = 0; j < 4; ++j) {
            // 16B unit index; wave-contiguous spans so LDS dest = base + lane*16
            int unit = j * 256 + tid;
            int row  = unit >> 3;                // 8 x 16B units per 64-col row
            int cu   = unit & 7;
            const __hip_bfloat16* gA = A + (size_t)(m0 + row) * K + kt + cu * 8;
            const __hip_bfloat16* gB = B + (size_t)(n0 + row) * K + kt + cu * 8;
            unsigned loff = (unsigned)((j * 256 + (wave << 6)) * 16); // wave-uniform
            __builtin_amdgcn_global_load_lds(
                (const __attribute__((address_space(1))) void*)gA,
                (__attribute__((address_space(3))) void*)((char*)sA + loff), 16, 0, 0);
            __builtin_amdgcn_global_load_lds(
                (const __attribute__((address_space(1))) void*)gB,
                (__attribute__((address_space(3))) void*)((char*)sB + loff), 16, 0, 0);
        }
        __syncthreads();   // compiler drains vmcnt before barrier -> LDS filled
#pragma unroll
        for (int kk = 0; kk < 2; ++kk) {
            bf16x8 af[4], bfr[4];
#pragma unroll
            for (int i = 0; i < 4; ++i) {
                af[i]  = *(const bf16x8*)&sA[(wm * 64 + i * 16 + lrow) * BK + kk * 32 + lkq * 8];
                bfr[i] = *(const bf16x8*)&sB[(wn * 64 + i * 16 + lrow) * BK + kk * 32 + lkq * 8];
            }
#pragma unroll
            for (int i = 0; i < 4; ++i)
#pragma unroll
                for (int jn = 0; jn < 4; ++jn)
                    acc[i][jn] = __builtin_amdgcn_mfma_f32_16x16x32_bf16(
                        af[i], bfr[jn], acc[i][jn], 0, 0, 0);
        }
    }

    // epilogue: C/D layout col = lane&15, row = (lane>>4)*4 + r  (m89/m91-verified)
#pragma unroll
    for (int jn = 0; jn < 4; ++jn) {
        int col = n0 + wn * 64 + jn * 16 + lrow;
        float bv = bias[col];
#pragma unroll
        for (int i = 0; i < 4; ++i) {
            int rbase = m0 + wm * 64 + i * 16 + lkq * 4;
#pragma unroll
            for (int r = 0; r < 4; ++r)
                C[(size_t)(rbase + r) * N + col] = acc[i][jn][r] + bv;
        }
    }
}

extern "C" void kernel_launch(void* const* d_in, const int* in_sizes, int n_in,
                              void* d_out, int out_size, void* d_ws, size_t ws_size,
                              hipStream_t stream) {
    const float* x      = (const float*)d_in[0];
    const int*   binary = (const int*)d_in[1];
    const float* scale  = (const float*)d_in[2];
    const float* bias   = (const float*)d_in[3];
    float* out = (float*)d_out;

    const int M = in_sizes[0] / NXX;   // 2*2048 = 4096 tokens

    // workspace: [xb: M*NX bf16 = 8MB][Wb: NF*NX bf16 = 8MB]
    __hip_bfloat16* xb = (__hip_bfloat16*)d_ws;
    __hip_bfloat16* Wb = xb + (size_t)M * NXX;

    k_cast_x<<<(M * NXX / 8) / 256, 256, 0, stream>>>(x, xb);
    k_decode_w<<<(NF * GRP) / 256, 256, 0, stream>>>(binary, scale, Wb);
    k_gemm_bt<<<dim3(NF / BN, M / BM), 256, 0, stream>>>(xb, Wb, bias, out, M, NF, NXX);
}

// Round 2
// 134.500 us; speedup vs baseline: 1.0942x; 1.0942x over previous
//
#include <hip/hip_runtime.h>
#include <hip/hip_bf16.h>
#include <stdint.h>

// out = x @ W^T + bias; W[f,n] = sum_k scale[k,f]*(bit(7-n%8) of binary[k,f,n/8] ? +1 : -1)
// Round 2: prep (cast x->bf16 + decode W->bf16) fused into one kernel, then
// 256x256 BK=64 8-wave phase-split MFMA GEMM (T1 XCD swizzle, T2 LDS XOR swizzle
// via pre-swizzled global source, T3/T4 counted-vmcnt double buffer, T5 setprio).

#define BITS 8
#define NF   4096
#define NXX  1024
#define GRP  (NXX / 8)

#define BM 256
#define BN 256
#define BK 64
#define NTHR 512

typedef __attribute__((ext_vector_type(4))) float f32x4;
typedef __attribute__((ext_vector_type(8))) short bf16x8;

// ---------------- prep: cast x (blocks 0..2047) + decode W (blocks 2048..4095) ----
__global__ __launch_bounds__(256) void k_prep(const float* __restrict__ x,
                                              const int* __restrict__ binary,
                                              const float* __restrict__ scale,
                                              __hip_bfloat16* __restrict__ xb,
                                              __hip_bfloat16* __restrict__ Wb) {
    const int b = blockIdx.x;
    const int tid = threadIdx.x;
    if (b < 2048) {
        int i = b * 256 + tid;
        const float4* xp = (const float4*)x;
        float4 a = xp[2 * i], c = xp[2 * i + 1];
        union { __hip_bfloat16 h[8]; int4 v; } u;
        u.h[0] = __float2bfloat16(a.x);
        u.h[1] = __float2bfloat16(a.y);
        u.h[2] = __float2bfloat16(a.z);
        u.h[3] = __float2bfloat16(a.w);
        u.h[4] = __float2bfloat16(c.x);
        u.h[5] = __float2bfloat16(c.y);
        u.h[6] = __float2bfloat16(c.z);
        u.h[7] = __float2bfloat16(c.w);
        ((int4*)xb)[i] = u.v;
    } else {
        int idx = (b - 2048) * 256 + tid;       // 0 .. NF*GRP-1
        int f = idx >> 7;                       // GRP = 128
        int g = idx & (GRP - 1);
        float sc[BITS];
        int   bv[BITS];
#pragma unroll
        for (int k = 0; k < BITS; ++k) {
            sc[k] = scale[k * NF + f];
            bv[k] = binary[(size_t)(k * NF + f) * GRP + g];
        }
        union { __hip_bfloat16 h[8]; int4 v; } u;
#pragma unroll
        for (int j = 0; j < 8; ++j) {           // element j uses bit (7-j)
            float s = 0.f;
#pragma unroll
            for (int k = 0; k < BITS; ++k)
                s += ((bv[k] >> (7 - j)) & 1) ? sc[k] : -sc[k];
            u.h[j] = __float2bfloat16(s);
        }
        ((int4*)Wb)[idx] = u.v;
    }
}

// ---------------- GEMM: C[M,N] = A[M,K] * B[N,K]^T + bias ----------------
// 512 thr = 8 waves (2 M x 4 N), per-wave out 128x64, acc[8][4] f32x4.
// LDS: 2 bufs x (A 32KB + B 32KB) = 128 KB. Swizzle: 16B-chunk q ^= (row&7).
__global__ __launch_bounds__(NTHR, 2) void k_gemm(const __hip_bfloat16* __restrict__ A,
                                                  const __hip_bfloat16* __restrict__ B,
                                                  const float* __restrict__ bias,
                                                  float* __restrict__ C,
                                                  int M, int N, int K) {
    __shared__ __align__(16) char lds[131072];

    const int tid  = threadIdx.x;
    const int lane = tid & 63;
    const int wid  = tid >> 6;
    const int wm = wid >> 2;        // 0..1
    const int wn = wid & 3;         // 0..3
    const int lr = lane & 15;       // fragment row/col
    const int lk = lane >> 4;       // K-octet 0..3

    // T1: XCD-aware swizzle (grid=256, 8 XCDs, 32 blocks each)
    const int nwg = gridDim.x;
    const int cpx = nwg >> 3;
    const int bid = blockIdx.x;
    const int swz = (bid & 7) * cpx + (bid >> 3);
    const int m0 = (swz >> 4) * BM;
    const int n0 = (swz & 15) * BN;

    const int NT = K / BK;          // 16

    // staging: 2048 16B-chunks per operand per tile; chunk c -> row r=c>>3,
    // slot q=c&7; source col-chunk pre-swizzled q^(r&7) so swizzled READ is linear.
    auto stageA = [&](int buf, int kt) {
        const __hip_bfloat16* src = A + (size_t)m0 * K + kt;
        char* dst = lds + buf * 65536;
#pragma unroll
        for (int j = 0; j < 4; ++j) {
            int c = j * 512 + tid;
            int r = c >> 3;
            int q = (c & 7) ^ (r & 7);
            __builtin_amdgcn_global_load_lds(
                (const __attribute__((address_space(1))) void*)(src + (size_t)r * K + q * 8),
                (__attribute__((address_space(3))) void*)(dst + j * 8192 + tid * 16), 16, 0, 0);
        }
    };
    auto stageB = [&](int buf, int kt) {
        const __hip_bfloat16* src = B + (size_t)n0 * K + kt;
        char* dst = lds + buf * 65536 + 32768;
#pragma unroll
        for (int j = 0; j < 4; ++j) {
            int c = j * 512 + tid;
            int r = c >> 3;
            int q = (c & 7) ^ (r & 7);
            __builtin_amdgcn_global_load_lds(
                (const __attribute__((address_space(1))) void*)(src + (size_t)r * K + q * 8),
                (__attribute__((address_space(3))) void*)(dst + j * 8192 + tid * 16), 16, 0, 0);
        }
    };
    // swizzled LDS reads: logical (row R, col-byte CB) -> CB ^ ((R&7)<<4)
    auto ldA = [&](int buf, int msub, int i, int kk) -> bf16x8 {
        int R = wm * 128 + msub * 64 + i * 16 + lr;
        int CB = (kk * 64 + lk * 16) ^ ((R & 7) << 4);
        return *(const bf16x8*)(lds + buf * 65536 + R * 128 + CB);
    };
    auto ldB = [&](int buf, int nsub, int j, int kk) -> bf16x8 {
        int R = wn * 64 + nsub * 32 + j * 16 + lr;
        int CB = (kk * 64 + lk * 16) ^ ((R & 7) << 4);
        return *(const bf16x8*)(lds + buf * 65536 + 32768 + R * 128 + CB);
    };

    f32x4 acc[8][4] = {};
    bf16x8 aF[4][2], bF0[2][2], bF1[2][2];

    // prologue: stage tile 0 into buf 0
    stageA(0, 0);
    stageB(0, 0);

    for (int t = 0; t < NT; ++t) {
        const int cb = t & 1;
        const bool st = (t + 1 < NT);
        // drain this tile's staging (issued >=2.5 phases ago in steady state)
        asm volatile("s_waitcnt vmcnt(0)" ::: "memory");
        __builtin_amdgcn_sched_barrier(0);
        __builtin_amdgcn_s_barrier();

        // ---- PH1: A-half0 frags + B n0,n1; prefetch A(t+1); MFMA q0 ----
#pragma unroll
        for (int i = 0; i < 4; ++i)
#pragma unroll
            for (int kk = 0; kk < 2; ++kk) aF[i][kk] = ldA(cb, 0, i, kk);
#pragma unroll
        for (int j = 0; j < 2; ++j)
#pragma unroll
            for (int kk = 0; kk < 2; ++kk) bF0[j][kk] = ldB(cb, 0, j, kk);
        if (st) stageA(cb ^ 1, (t + 1) * BK);
        __builtin_amdgcn_s_barrier();
        asm volatile("s_waitcnt lgkmcnt(0)" ::: "memory");
        __builtin_amdgcn_sched_barrier(0);
        __builtin_amdgcn_s_setprio(1);
#pragma unroll
        for (int i = 0; i < 4; ++i)
#pragma unroll
            for (int j = 0; j < 2; ++j)
#pragma unroll
                for (int kk = 0; kk < 2; ++kk)
                    acc[i][j] = __builtin_amdgcn_mfma_f32_16x16x32_bf16(aF[i][kk], bF0[j][kk], acc[i][j], 0, 0, 0);
        __builtin_amdgcn_s_setprio(0);
        __builtin_amdgcn_sched_barrier(0);
        __builtin_amdgcn_s_barrier();

        // ---- PH2: B n2,n3; prefetch B(t+1); MFMA q1 ----
#pragma unroll
        for (int j = 0; j < 2; ++j)
#pragma unroll
            for (int kk = 0; kk < 2; ++kk) bF1[j][kk] = ldB(cb, 1, j, kk);
        if (st) stageB(cb ^ 1, (t + 1) * BK);
        __builtin_amdgcn_s_barrier();
        asm volatile("s_waitcnt lgkmcnt(0)" ::: "memory");
        __builtin_amdgcn_sched_barrier(0);
        __builtin_amdgcn_s_setprio(1);
#pragma unroll
        for (int i = 0; i < 4; ++i)
#pragma unroll
            for (int j = 0; j < 2; ++j)
#pragma unroll
                for (int kk = 0; kk < 2; ++kk)
                    acc[i][2 + j] = __builtin_amdgcn_mfma_f32_16x16x32_bf16(aF[i][kk], bF1[j][kk], acc[i][2 + j], 0, 0, 0);
        __builtin_amdgcn_s_setprio(0);
        __builtin_amdgcn_sched_barrier(0);
        __builtin_amdgcn_s_barrier();

        // ---- PH3: A-half1 frags; MFMA q2 ----
#pragma unroll
        for (int i = 0; i < 4; ++i)
#pragma unroll
            for (int kk = 0; kk < 2; ++kk) aF[i][kk] = ldA(cb, 1, i, kk);
        __builtin_amdgcn_s_barrier();
        asm volatile("s_waitcnt lgkmcnt(0)" ::: "memory");
        __builtin_amdgcn_sched_barrier(0);
        __builtin_amdgcn_s_setprio(1);
#pragma unroll
        for (int i = 0; i < 4; ++i)
#pragma unroll
            for (int j = 0; j < 2; ++j)
#pragma unroll
                for (int kk = 0; kk < 2; ++kk)
                    acc[4 + i][j] = __builtin_amdgcn_mfma_f32_16x16x32_bf16(aF[i][kk], bF0[j][kk], acc[4 + i][j], 0, 0, 0);
        __builtin_amdgcn_s_setprio(0);
        __builtin_amdgcn_sched_barrier(0);
        __builtin_amdgcn_s_barrier();

        // ---- PH4: MFMA q3 (regs only) ----
        __builtin_amdgcn_s_setprio(1);
#pragma unroll
        for (int i = 0; i < 4; ++i)
#pragma unroll
            for (int j = 0; j < 2; ++j)
#pragma unroll
                for (int kk = 0; kk < 2; ++kk)
                    acc[4 + i][2 + j] = __builtin_amdgcn_mfma_f32_16x16x32_bf16(aF[i][kk], bF1[j][kk], acc[4 + i][2 + j], 0, 0, 0);
        __builtin_amdgcn_s_setprio(0);
        __builtin_amdgcn_sched_barrier(0);
        __builtin_amdgcn_s_barrier();
    }

    // epilogue: C/D layout col = lane&15, row = (lane>>4)*4 + r
#pragma unroll
    for (int j = 0; j < 4; ++j) {
        int col = n0 + wn * 64 + j * 16 + lr;
        float bv = bias[col];
#pragma unroll
        for (int i = 0; i < 8; ++i) {
            int row = m0 + wm * 128 + i * 16 + lk * 4;
#pragma unroll
            for (int r = 0; r < 4; ++r)
                C[(size_t)(row + r) * N + col] = acc[i][j][r] + bv;
        }
    }
}

extern "C" void kernel_launch(void* const* d_in, const int* in_sizes, int n_in,
                              void* d_out, int out_size, void* d_ws, size_t ws_size,
                              hipStream_t stream) {
    const float* x      = (const float*)d_in[0];
    const int*   binary = (const int*)d_in[1];
    const float* scale  = (const float*)d_in[2];
    const float* bias   = (const float*)d_in[3];
    float* out = (float*)d_out;

    const int M = in_sizes[0] / NXX;   // 4096 tokens

    __hip_bfloat16* xb = (__hip_bfloat16*)d_ws;                 // 8 MB
    __hip_bfloat16* Wb = xb + (size_t)M * NXX;                  // 8 MB

    k_prep<<<2048 + (NF * GRP) / 256, 256, 0, stream>>>(x, binary, scale, xb, Wb);
    k_gemm<<<(M / BM) * (NF / BN), NTHR, 0, stream>>>(xb, Wb, bias, out, M, NF, NXX);
}

// Round 3
// 133.060 us; speedup vs baseline: 1.1061x; 1.0108x over previous
//
#include <hip/hip_runtime.h>
#include <hip/hip_bf16.h>
#include <stdint.h>

// out = x @ W^T + bias; W[f,n] = sum_k scale[k,f]*(bit(7-n%8) of binary[k,f,n/8] ? +1 : -1)
// Round 3: true m201 8-phase schedule — 2 K-tiles/iter, half-tile staging
// (2 gload_lds/phase), counted vmcnt(6) at phases 4+8 only, T1/T2/T5 kept.

#define BITS 8
#define NF   4096
#define NXX  1024
#define GRP  (NXX / 8)

#define BM 256
#define BN 256
#define BK 64
#define NTHR 512

typedef __attribute__((ext_vector_type(4))) float f32x4;
typedef __attribute__((ext_vector_type(8))) short bf16x8;

// ---------------- prep: cast x (blocks 0..2047) + decode W (blocks 2048..4095) ----
__global__ __launch_bounds__(256) void k_prep(const float* __restrict__ x,
                                              const int* __restrict__ binary,
                                              const float* __restrict__ scale,
                                              __hip_bfloat16* __restrict__ xb,
                                              __hip_bfloat16* __restrict__ Wb) {
    const int b = blockIdx.x;
    const int tid = threadIdx.x;
    if (b < 2048) {
        int i = b * 256 + tid;
        const float4* xp = (const float4*)x;
        float4 a = xp[2 * i], c = xp[2 * i + 1];
        union { __hip_bfloat16 h[8]; int4 v; } u;
        u.h[0] = __float2bfloat16(a.x);
        u.h[1] = __float2bfloat16(a.y);
        u.h[2] = __float2bfloat16(a.z);
        u.h[3] = __float2bfloat16(a.w);
        u.h[4] = __float2bfloat16(c.x);
        u.h[5] = __float2bfloat16(c.y);
        u.h[6] = __float2bfloat16(c.z);
        u.h[7] = __float2bfloat16(c.w);
        ((int4*)xb)[i] = u.v;
    } else {
        int idx = (b - 2048) * 256 + tid;       // 0 .. NF*GRP-1
        int f = idx >> 7;                       // GRP = 128
        int g = idx & (GRP - 1);
        float sc[BITS];
        int   bv[BITS];
#pragma unroll
        for (int k = 0; k < BITS; ++k) {
            sc[k] = scale[k * NF + f];
            bv[k] = binary[(size_t)(k * NF + f) * GRP + g];
        }
        union { __hip_bfloat16 h[8]; int4 v; } u;
#pragma unroll
        for (int j = 0; j < 8; ++j) {           // element j uses bit (7-j)
            float s = 0.f;
#pragma unroll
            for (int k = 0; k < BITS; ++k)
                s += ((bv[k] >> (7 - j)) & 1) ? sc[k] : -sc[k];
            u.h[j] = __float2bfloat16(s);
        }
        ((int4*)Wb)[idx] = u.v;
    }
}

// ---------------- GEMM: C[M,N] = A[M,K] * B[N,K]^T + bias ----------------
// 512 thr = 8 waves (2M x 4N), per-wave out 128x64, acc[8][4] f32x4.
// LDS: 2 bufs x (A 32KB + B 32KB) = 128 KB. T2 swizzle: 16B-chunk q ^= (R&7).
// 8-phase / 2-K-tile iteration, half-tile stage units:
//   A_f rows {0-63,128-191}, A_b {64-127,192-255},
//   B_f rows {0-31,64-95,128-159,192-223}, B_b the complement.
// Stage ring: PH1 buf1.A_f(tile 2i+1); PH2-5 buf0.{B_f,B_b,A_b,A_f}(2i+2);
// PH6-8 buf1.{B_f,B_b,A_b}(2i+3). vmcnt(6) at PH4+PH8 only.
__global__ __launch_bounds__(NTHR, 2) void k_gemm(const __hip_bfloat16* __restrict__ A,
                                                  const __hip_bfloat16* __restrict__ B,
                                                  const float* __restrict__ bias,
                                                  float* __restrict__ C,
                                                  int M, int N, int K) {
    __shared__ __align__(16) char lds[131072];

    const int tid  = threadIdx.x;
    const int lane = tid & 63;
    const int wid  = tid >> 6;
    const int wm = wid >> 2;        // 0..1
    const int wn = wid & 3;         // 0..3
    const int lr = lane & 15;       // fragment row/col
    const int lk = lane >> 4;       // K-octet 0..3

    // T1: XCD-aware swizzle (grid=256 -> cpx=32, bijective)
    const int nwg = gridDim.x;
    const int cpx = nwg >> 3;
    const int bid = blockIdx.x;
    const int swz = (bid & 7) * cpx + (bid >> 3);
    const int m0 = (swz >> 4) * BM;
    const int n0 = (swz & 15) * BN;

    const int NT = K / BK;          // 16 K-tiles
    const int NI = NT / 2;          // 8 iterations

    // ---- half-tile stage: kind 0=A_f 1=A_b 2=B_f 3=B_b; 2 gload_lds/thread ----
    auto stage_unit = [&](int buf, int kt, int kind) {
        const bool isA = (kind < 2);
        const __hip_bfloat16* src = (isA ? A + (size_t)m0 * K : B + (size_t)n0 * K) + kt;
        char* base = lds + buf * 65536 + (isA ? 0 : 32768);
        int lrr = tid >> 3;          // 0..63
        int q   = tid & 7;
        int R0;
        if (isA) R0 = ((kind == 1) ? 64 : 0) + lrr;
        else     R0 = ((kind == 3) ? 32 : 0) + (lrr & 31) + ((lrr & 32) << 1);
#pragma unroll
        for (int call = 0; call < 2; ++call) {
            int R  = R0 + call * 128;
            int qs = q ^ (R & 7);            // pre-swizzled source (T2, rule #21)
            __builtin_amdgcn_global_load_lds(
                (const __attribute__((address_space(1))) void*)(src + (size_t)R * K + qs * 8),
                (__attribute__((address_space(3))) void*)(base + R * 128 + q * 16), 16, 0, 0);
        }
    };
    // swizzled LDS reads: logical (row R, col-byte CB) -> CB ^ ((R&7)<<4)
    auto ldA = [&](int buf, int msub, int i, int kk) -> bf16x8 {
        int R = wm * 128 + msub * 64 + i * 16 + lr;
        int CB = (kk * 64 + lk * 16) ^ ((R & 7) << 4);
        return *(const bf16x8*)(lds + buf * 65536 + R * 128 + CB);
    };
    auto ldB = [&](int buf, int nsub, int j, int kk) -> bf16x8 {
        int R = wn * 64 + nsub * 32 + j * 16 + lr;
        int CB = (kk * 64 + lk * 16) ^ ((R & 7) << 4);
        return *(const bf16x8*)(lds + buf * 65536 + 32768 + R * 128 + CB);
    };

    f32x4 acc[8][4] = {};
    bf16x8 aF[4][2], bF0[2][2], bF1[2][2];

#define BAR()   __builtin_amdgcn_s_barrier()
#define LGKM0() do { asm volatile("s_waitcnt lgkmcnt(0)" ::: "memory"); \
                     __builtin_amdgcn_sched_barrier(0); } while (0)
#define VM6()   do { __builtin_amdgcn_sched_barrier(0); \
                     asm volatile("s_waitcnt vmcnt(6)" ::: "memory"); } while (0)
#define PRIO1() __builtin_amdgcn_s_setprio(1)
#define PRIO0() do { __builtin_amdgcn_s_setprio(0); \
                     __builtin_amdgcn_sched_barrier(0); } while (0)
#define MFMA_Q(ms, ns, BF)                                                         \
    do {                                                                           \
        _Pragma("unroll") for (int i = 0; i < 4; ++i)                              \
        _Pragma("unroll") for (int j = 0; j < 2; ++j)                              \
        _Pragma("unroll") for (int kk = 0; kk < 2; ++kk)                           \
            acc[(ms)*4 + i][(ns)*2 + j] = __builtin_amdgcn_mfma_f32_16x16x32_bf16( \
                aF[i][kk], BF[j][kk], acc[(ms)*4 + i][(ns)*2 + j], 0, 0, 0);       \
    } while (0)

    // ---- prologue: tile0 all 4 units + tile1 {B_f,B_b,A_b}; retire tile0 ----
    stage_unit(0, 0, 0); stage_unit(0, 0, 2); stage_unit(0, 0, 3); stage_unit(0, 0, 1);
    stage_unit(1, BK, 2); stage_unit(1, BK, 3); stage_unit(1, BK, 1);
    asm volatile("s_waitcnt vmcnt(6)" ::: "memory");
    BAR();

    for (int it = 0; it < NI; ++it) {
        const int to = 2 * it + 1;
        const int tn = 2 * it + 2;        // next even tile
        const bool st = (it + 1 < NI);

        // PH1: reads buf0 A_f(msub0) + B_f(nsub0); stage buf1.A_f(tile to)
#pragma unroll
        for (int i = 0; i < 4; ++i) { aF[i][0] = ldA(0, 0, i, 0); aF[i][1] = ldA(0, 0, i, 1); }
#pragma unroll
        for (int j = 0; j < 2; ++j) { bF0[j][0] = ldB(0, 0, j, 0); bF0[j][1] = ldB(0, 0, j, 1); }
        stage_unit(1, to * BK, 0);
        BAR(); LGKM0(); PRIO1(); MFMA_Q(0, 0, bF0); PRIO0(); BAR();

        // PH2: reads buf0 B_b(nsub1); stage buf0.B_f(tn)
#pragma unroll
        for (int j = 0; j < 2; ++j) { bF1[j][0] = ldB(0, 1, j, 0); bF1[j][1] = ldB(0, 1, j, 1); }
        if (st) stage_unit(0, tn * BK, 2);
        BAR(); LGKM0(); PRIO1(); MFMA_Q(0, 1, bF1); PRIO0(); BAR();

        // PH3: reads buf0 A_b(msub1); stage buf0.B_b(tn)
#pragma unroll
        for (int i = 0; i < 4; ++i) { aF[i][0] = ldA(0, 1, i, 0); aF[i][1] = ldA(0, 1, i, 1); }
        if (st) stage_unit(0, tn * BK, 3);
        BAR(); LGKM0(); PRIO1(); MFMA_Q(1, 0, bF0); PRIO0(); BAR();

        // PH4: no reads; stage buf0.A_b(tn); vmcnt(6) retires through PH1's stage
        if (st) stage_unit(0, tn * BK, 1);
        BAR(); PRIO1(); MFMA_Q(1, 1, bF1); PRIO0(); VM6(); BAR();

        // PH5: reads buf1 A_f + B_f (tile to); stage buf0.A_f(tn)
#pragma unroll
        for (int i = 0; i < 4; ++i) { aF[i][0] = ldA(1, 0, i, 0); aF[i][1] = ldA(1, 0, i, 1); }
#pragma unroll
        for (int j = 0; j < 2; ++j) { bF0[j][0] = ldB(1, 0, j, 0); bF0[j][1] = ldB(1, 0, j, 1); }
        if (st) stage_unit(0, tn * BK, 0);
        BAR(); LGKM0(); PRIO1(); MFMA_Q(0, 0, bF0); PRIO0(); BAR();

        // PH6: reads buf1 B_b; stage buf1.B_f(tn+1)
#pragma unroll
        for (int j = 0; j < 2; ++j) { bF1[j][0] = ldB(1, 1, j, 0); bF1[j][1] = ldB(1, 1, j, 1); }
        if (st) stage_unit(1, (tn + 1) * BK, 2);
        BAR(); LGKM0(); PRIO1(); MFMA_Q(0, 1, bF1); PRIO0(); BAR();

        // PH7: reads buf1 A_b; stage buf1.B_b(tn+1)
#pragma unroll
        for (int i = 0; i < 4; ++i) { aF[i][0] = ldA(1, 1, i, 0); aF[i][1] = ldA(1, 1, i, 1); }
        if (st) stage_unit(1, (tn + 1) * BK, 3);
        BAR(); LGKM0(); PRIO1(); MFMA_Q(1, 0, bF0); PRIO0(); BAR();

        // PH8: no reads; stage buf1.A_b(tn+1); vmcnt(6) retires through PH5's stage
        if (st) stage_unit(1, (tn + 1) * BK, 1);
        BAR(); PRIO1(); MFMA_Q(1, 1, bF1); PRIO0(); VM6(); BAR();
    }

#undef BAR
#undef LGKM0
#undef VM6
#undef PRIO1
#undef PRIO0
#undef MFMA_Q

    // epilogue: C/D layout col = lane&15, row = (lane>>4)*4 + r
#pragma unroll
    for (int j = 0; j < 4; ++j) {
        int col = n0 + wn * 64 + j * 16 + lr;
        float bv = bias[col];
#pragma unroll
        for (int i = 0; i < 8; ++i) {
            int row = m0 + wm * 128 + i * 16 + lk * 4;
#pragma unroll
            for (int r = 0; r < 4; ++r)
                C[(size_t)(row + r) * N + col] = acc[i][j][r] + bv;
        }
    }
}

extern "C" void kernel_launch(void* const* d_in, const int* in_sizes, int n_in,
                              void* d_out, int out_size, void* d_ws, size_t ws_size,
                              hipStream_t stream) {
    const float* x      = (const float*)d_in[0];
    const int*   binary = (const int*)d_in[1];
    const float* scale  = (const float*)d_in[2];
    const float* bias   = (const float*)d_in[3];
    float* out = (float*)d_out;

    const int M = in_sizes[0] / NXX;   // 4096 tokens

    __hip_bfloat16* xb = (__hip_bfloat16*)d_ws;                 // 8 MB
    __hip_bfloat16* Wb = xb + (size_t)M * NXX;                  // 8 MB

    k_prep<<<2048 + (NF * GRP) / 256, 256, 0, stream>>>(x, binary, scale, xb, Wb);
    k_gemm<<<(M / BM) * (NF / BN), NTHR, 0, stream>>>(xb, Wb, bias, out, M, NF, NXX);
}

// Round 4
// 131.675 us; speedup vs baseline: 1.1177x; 1.0105x over previous
//
#include <hip/hip_runtime.h>
#include <hip/hip_bf16.h>
#include <stdint.h>

// out = x @ W^T + bias; W[f,n] = sum_k scale[k,f]*(bit(7-n%8) of binary[k,f,n/8] ? +1 : -1)
// Round 4: tails were the bottleneck (1 block/CU -> serial prologue/epilogue).
// New GEMM: 128x256 tile, grid 512 = 2 blocks/CU, 4 waves, single-buffered
// 48KB LDS, 2-syncthreads loop; cross-block overlap hides stage + C-write tails.
// T1 XCD swizzle + T2 LDS XOR swizzle + T5 setprio kept.

#define BITS 8
#define NF   4096
#define NXX  1024
#define GRP  (NXX / 8)

#define BM 128
#define BN 256
#define BK 64

typedef __attribute__((ext_vector_type(4))) float f32x4;
typedef __attribute__((ext_vector_type(8))) short bf16x8;

// ---------------- prep: cast x (blocks 0..2047) + decode W (blocks 2048..4095) ----
__global__ __launch_bounds__(256) void k_prep(const float* __restrict__ x,
                                              const int* __restrict__ binary,
                                              const float* __restrict__ scale,
                                              __hip_bfloat16* __restrict__ xb,
                                              __hip_bfloat16* __restrict__ Wb) {
    const int b = blockIdx.x;
    const int tid = threadIdx.x;
    if (b < 2048) {
        int i = b * 256 + tid;
        const float4* xp = (const float4*)x;
        float4 a = xp[2 * i], c = xp[2 * i + 1];
        union { __hip_bfloat16 h[8]; int4 v; } u;
        u.h[0] = __float2bfloat16(a.x);
        u.h[1] = __float2bfloat16(a.y);
        u.h[2] = __float2bfloat16(a.z);
        u.h[3] = __float2bfloat16(a.w);
        u.h[4] = __float2bfloat16(c.x);
        u.h[5] = __float2bfloat16(c.y);
        u.h[6] = __float2bfloat16(c.z);
        u.h[7] = __float2bfloat16(c.w);
        ((int4*)xb)[i] = u.v;
    } else {
        int idx = (b - 2048) * 256 + tid;       // 0 .. NF*GRP-1
        int f = idx >> 7;                       // GRP = 128
        int g = idx & (GRP - 1);
        float sc[BITS];
        int   bv[BITS];
#pragma unroll
        for (int k = 0; k < BITS; ++k) {
            sc[k] = scale[k * NF + f];
            bv[k] = binary[(size_t)(k * NF + f) * GRP + g];
        }
        union { __hip_bfloat16 h[8]; int4 v; } u;
#pragma unroll
        for (int j = 0; j < 8; ++j) {           // element j uses bit (7-j)
            float s = 0.f;
#pragma unroll
            for (int k = 0; k < BITS; ++k)
                s += ((bv[k] >> (7 - j)) & 1) ? sc[k] : -sc[k];
            u.h[j] = __float2bfloat16(s);
        }
        ((int4*)Wb)[idx] = u.v;
    }
}

// ---------------- GEMM: C[M,N] = A[M,K] * B[N,K]^T + bias ----------------
// 256 thr = 4 waves; wave w owns N-cols [w*64, w*64+64), all 128 M-rows.
// acc[8][4] f32x4 (128 VGPR). LDS: sA 16KB + sB 32KB, single buffer.
// Loop: sync (stage(t) drained) -> ds_read bF + aF(half0) -> MFMA half0 ->
//       ds_read aF(half1) -> sync (reads done) -> stage(t+1) -> MFMA half1.
__global__ __launch_bounds__(256, 2) void k_gemm(const __hip_bfloat16* __restrict__ A,
                                                 const __hip_bfloat16* __restrict__ B,
                                                 const float* __restrict__ bias,
                                                 float* __restrict__ C,
                                                 int M, int N, int K) {
    __shared__ __align__(16) char lds[49152];

    const int tid  = threadIdx.x;
    const int lane = tid & 63;
    const int wv   = tid >> 6;      // 0..3
    const int lr = lane & 15;       // fragment row/col
    const int lk = lane >> 4;       // K-octet 0..3

    // T1: XCD swizzle. grid=512, 64 blocks/XCD: m_t = swz&31, n_t = swz>>5
    // (each XCD covers 2 n-panels x all 32 m -> B reused 32x within XCD).
    const int bid = blockIdx.x;
    const int swz = (bid & 7) * 64 + (bid >> 3);
    const int m0 = (swz & 31) * BM;
    const int n0 = (swz >> 5) * BN;

    const int NT = K / BK;          // 16

    // per-thread staging constants (T2: source chunk pre-swizzled, LDS dest linear)
    int offA[4], dstA[4], offB[8], dstB[8];
#pragma unroll
    for (int j = 0; j < 4; ++j) {
        int c = j * 256 + tid, r = c >> 3, q = c & 7;
        offA[j] = r * K + (q ^ (r & 7)) * 8;
        dstA[j] = c * 16;
    }
#pragma unroll
    for (int j = 0; j < 8; ++j) {
        int c = j * 256 + tid, r = c >> 3, q = c & 7;
        offB[j] = r * K + (q ^ (r & 7)) * 8;
        dstB[j] = 16384 + c * 16;
    }
    const __hip_bfloat16* Abase = A + (size_t)m0 * K;
    const __hip_bfloat16* Bbase = B + (size_t)n0 * K;

    auto stage = [&](int kt) {
#pragma unroll
        for (int j = 0; j < 4; ++j)
            __builtin_amdgcn_global_load_lds(
                (const __attribute__((address_space(1))) void*)(Abase + offA[j] + kt),
                (__attribute__((address_space(3))) void*)(lds + dstA[j]), 16, 0, 0);
#pragma unroll
        for (int j = 0; j < 8; ++j)
            __builtin_amdgcn_global_load_lds(
                (const __attribute__((address_space(1))) void*)(Bbase + offB[j] + kt),
                (__attribute__((address_space(3))) void*)(lds + dstB[j]), 16, 0, 0);
    };
    // swizzled LDS reads: logical (row R, col-byte CB) -> CB ^ ((R&7)<<4)
    auto ldA = [&](int i, int kk) -> bf16x8 {
        int R = i * 16 + lr;
        int CB = (kk * 64 + lk * 16) ^ ((R & 7) << 4);
        return *(const bf16x8*)(lds + R * 128 + CB);
    };
    auto ldB = [&](int j, int kk) -> bf16x8 {
        int R = wv * 64 + j * 16 + lr;
        int CB = (kk * 64 + lk * 16) ^ ((R & 7) << 4);
        return *(const bf16x8*)(lds + 16384 + R * 128 + CB);
    };

    f32x4 acc[8][4] = {};
    bf16x8 aF[4][2], bF[4][2];

    stage(0);
    for (int t = 0; t < NT; ++t) {
        __syncthreads();            // stage(t) drained (vmcnt 0) + all waves ready
#pragma unroll
        for (int j = 0; j < 4; ++j) { bF[j][0] = ldB(j, 0); bF[j][1] = ldB(j, 1); }
#pragma unroll
        for (int i = 0; i < 4; ++i) { aF[i][0] = ldA(i, 0); aF[i][1] = ldA(i, 1); }
        __builtin_amdgcn_s_setprio(1);
#pragma unroll
        for (int i = 0; i < 4; ++i)
#pragma unroll
            for (int j = 0; j < 4; ++j)
#pragma unroll
                for (int kk = 0; kk < 2; ++kk)
                    acc[i][j] = __builtin_amdgcn_mfma_f32_16x16x32_bf16(
                        aF[i][kk], bF[j][kk], acc[i][j], 0, 0, 0);
        __builtin_amdgcn_s_setprio(0);
#pragma unroll
        for (int i = 0; i < 4; ++i) { aF[i][0] = ldA(4 + i, 0); aF[i][1] = ldA(4 + i, 1); }
        __syncthreads();            // all waves' LDS reads complete -> safe to overwrite
        if (t + 1 < NT) stage((t + 1) * BK);   // HBM latency hides under MFMA half1
        __builtin_amdgcn_s_setprio(1);
#pragma unroll
        for (int i = 0; i < 4; ++i)
#pragma unroll
            for (int j = 0; j < 4; ++j)
#pragma unroll
                for (int kk = 0; kk < 2; ++kk)
                    acc[4 + i][j] = __builtin_amdgcn_mfma_f32_16x16x32_bf16(
                        aF[i][kk], bF[j][kk], acc[4 + i][j], 0, 0, 0);
        __builtin_amdgcn_s_setprio(0);
    }

    // epilogue: C/D layout col = lane&15, row = (lane>>4)*4 + r
#pragma unroll
    for (int j = 0; j < 4; ++j) {
        int col = n0 + wv * 64 + j * 16 + lr;
        float bv = bias[col];
#pragma unroll
        for (int i = 0; i < 8; ++i) {
            int row = m0 + i * 16 + lk * 4;
#pragma unroll
            for (int r = 0; r < 4; ++r)
                C[(size_t)(row + r) * N + col] = acc[i][j][r] + bv;
        }
    }
}

extern "C" void kernel_launch(void* const* d_in, const int* in_sizes, int n_in,
                              void* d_out, int out_size, void* d_ws, size_t ws_size,
                              hipStream_t stream) {
    const float* x      = (const float*)d_in[0];
    const int*   binary = (const int*)d_in[1];
    const float* scale  = (const float*)d_in[2];
    const float* bias   = (const float*)d_in[3];
    float* out = (float*)d_out;

    const int M = in_sizes[0] / NXX;   // 4096 tokens

    __hip_bfloat16* xb = (__hip_bfloat16*)d_ws;                 // 8 MB
    __hip_bfloat16* Wb = xb + (size_t)M * NXX;                  // 8 MB

    k_prep<<<2048 + (NF * GRP) / 256, 256, 0, stream>>>(x, binary, scale, xb, Wb);
    k_gemm<<<(M / BM) * (NF / BN), 256, 0, stream>>>(xb, Wb, bias, out, M, NF, NXX);
}